// Round 4
// baseline (337.161 us; speedup 1.0000x reference)
//
#include <hip/hip_runtime.h>

// GranularMoELayer: B=8192, D_IN=1024, D_OUT=1024, E=8, K=2, H=2048
// Sparse top-2 routing (atomic-free, deterministic) + bf16 MFMA grouped GEMMs.
// R4: structural port of both GEMMs to the 256x256 / BK=64 / 8-wave phase-split
//     template (catalog T3+T4, m201/m248): 4 phases per K-tile, each
//     {ds_read subtile -> barrier -> setprio(1) 16xMFMA setprio(0) -> barrier},
//     boundary vmcnt(0) with a FULL TILE of cover (loads issued at phase 0 of
//     the previous tile), T2 XOR-swizzle (both sides: pre-swizzled global src +
//     swizzled ds_read) so BK=64's 16-way bank conflict becomes conflict-free.
//     1 block/CU (128 KiB LDS), 256-row chunk table for the grouped grid.

#define NTOK 8192
#define DIN  1024
#define DOUT 1024
#define NEXP 8
#define NHID 2048
#define NENT (NTOK * 2)          // 16384 routing entries
#define ABLK 64                  // assign/hist blocks (256 entries each)
#define MCHMAX 72                // >= sum_e ceil(count_e/256) (<=71); 72%8==0

typedef __bf16 bf16_t;
typedef __bf16 bf16x8 __attribute__((ext_vector_type(8)));
typedef __bf16 bf16x4 __attribute__((ext_vector_type(4)));
typedef float  f32x4  __attribute__((ext_vector_type(4)));

// CK-style address-space casts for global_load_lds
#define AS3(p) ((__attribute__((address_space(3))) void*)(unsigned)(unsigned long long)(p))
#define AS1(p) ((__attribute__((address_space(1))) void*)(unsigned long long)(p))

static __device__ __forceinline__ int imin_(int a, int b) { return a < b ? a : b; }

// XCD-aware bijective swizzle (gridDim.x % 8 == 0).
static __device__ __forceinline__ int xcd_swizzle() {
    int cpx = gridDim.x >> 3;
    return (blockIdx.x & 7) * cpx + (blockIdx.x >> 3);
}

// ---------------------------------------------------------------------------
// Transpose + f32->bf16 convert:  W[E][K_][N_] (f32) -> WT[E][N_][K_] (bf16)
// ---------------------------------------------------------------------------
__global__ __launch_bounds__(256) void k_transpose_cvt(
    const float* __restrict__ W, bf16_t* __restrict__ WT, int K_, int N_)
{
    __shared__ float tile[64][65];
    const int tilesK = K_ >> 6, tilesN = N_ >> 6;
    int bid = blockIdx.x;
    int e = bid / (tilesK * tilesN);
    int r = bid % (tilesK * tilesN);
    int tk = (r / tilesN) << 6;
    int tn = (r % tilesN) << 6;
    const float* Wb  = W  + (size_t)e * K_ * N_;
    bf16_t*      WTb = WT + (size_t)e * K_ * N_;
    int lr = threadIdx.x >> 6;   // 0..3
    int lc = threadIdx.x & 63;   // 0..63
#pragma unroll
    for (int i = 0; i < 16; ++i) {
        int row = i * 4 + lr;
        tile[row][lc] = Wb[(size_t)(tk + row) * N_ + tn + lc];
    }
    __syncthreads();
#pragma unroll
    for (int i = 0; i < 16; ++i) {
        int row = i * 4 + lr;
        WTb[(size_t)(tn + row) * K_ + tk + lc] = (bf16_t)tile[lc][row];
    }
}

// ---------------------------------------------------------------------------
// Tiny transpose: Wg[DIN][E] (f32) -> WgT[E][DIN] (f32)
// ---------------------------------------------------------------------------
__global__ __launch_bounds__(256) void k_wgT(
    const float* __restrict__ Wg, float* __restrict__ WgT)
{
    int i = blockIdx.x * 256 + threadIdx.x;
    int d = i >> 3, e = i & 7;
    WgT[e * DIN + d] = Wg[i];
}

// ---------------------------------------------------------------------------
// Gating: scores = x@Wg + bg (f32), top-2 -> topk. NO atomics.
// Fused: writes xb = bf16(x). One wave per token, all loads coalesced.
// ---------------------------------------------------------------------------
__global__ __launch_bounds__(256) void k_gating(
    const float* __restrict__ x, const float* __restrict__ WgT,
    const float* __restrict__ bg, bf16_t* __restrict__ xb,
    int* __restrict__ topk)
{
    int lane = threadIdx.x & 63;
    int tok  = blockIdx.x * 4 + (threadIdx.x >> 6);
    const float* xr  = x  + (size_t)tok * DIN;
    bf16_t*      xbr = xb + (size_t)tok * DIN;

    float4 xv[4];
#pragma unroll
    for (int i = 0; i < 4; ++i) {
        int idx = i * 256 + lane * 4;
        xv[i] = *reinterpret_cast<const float4*>(xr + idx);
        bf16x4 o;
        o[0] = (bf16_t)xv[i].x; o[1] = (bf16_t)xv[i].y;
        o[2] = (bf16_t)xv[i].z; o[3] = (bf16_t)xv[i].w;
        *reinterpret_cast<bf16x4*>(xbr + idx) = o;
    }

    float acc[NEXP];
#pragma unroll
    for (int e = 0; e < NEXP; ++e) {
        const float* we = WgT + (size_t)e * DIN;
        float a = 0.f;
#pragma unroll
        for (int i = 0; i < 4; ++i) {
            int idx = i * 256 + lane * 4;
            float4 w = *reinterpret_cast<const float4*>(we + idx);
            a += xv[i].x * w.x + xv[i].y * w.y + xv[i].z * w.z + xv[i].w * w.w;
        }
        acc[e] = a;
    }

#pragma unroll
    for (int e = 0; e < NEXP; ++e) {
#pragma unroll
        for (int off = 32; off >= 1; off >>= 1) acc[e] += __shfl_xor(acc[e], off);
    }
    if (lane == 0) {
        float s[NEXP];
#pragma unroll
        for (int e = 0; e < NEXP; ++e) s[e] = acc[e] + bg[e];
        int e0 = 0;
        for (int e = 1; e < NEXP; ++e) if (s[e] > s[e0]) e0 = e;   // ties -> lower idx
        int e1 = (e0 == 0) ? 1 : 0;
        for (int e = 0; e < NEXP; ++e) if (e != e0 && s[e] > s[e1]) e1 = e;
        topk[2 * tok]     = e0;
        topk[2 * tok + 1] = e1;
    }
}

// ---------------------------------------------------------------------------
// Per-block histogram of expert ids (LDS atomics only). ABLK blocks x 256.
// ---------------------------------------------------------------------------
__global__ __launch_bounds__(256) void k_hist(
    const int* __restrict__ topk, int* __restrict__ bh)
{
    __shared__ int h[NEXP];
    if (threadIdx.x < NEXP) h[threadIdx.x] = 0;
    __syncthreads();
    int i = blockIdx.x * 256 + threadIdx.x;
    atomicAdd(&h[topk[i]], 1);                 // LDS-scope, cheap
    __syncthreads();
    if (threadIdx.x < NEXP) bh[blockIdx.x * NEXP + threadIdx.x] = h[threadIdx.x];
}

// ---------------------------------------------------------------------------
// Scan: counts[e], offsets[9], per-block bases blockbase[ABLK][E]. 1 block.
// Builds the compact 256-row M-chunk table: chtab[n] = (e<<16)|mc;
// nch[0] = live chunks. chtab ALIASES bh (consumed first).
// ---------------------------------------------------------------------------
__global__ void k_scan2(const int* __restrict__ bh, int* __restrict__ counts,
                        int* __restrict__ offsets, int* __restrict__ blockbase,
                        int* __restrict__ chtab, int* __restrict__ nch)
{
    __shared__ int sc[NEXP], so_[NEXP + 1];
    int t = threadIdx.x;
    if (t < NEXP) {
        int s = 0;
        for (int b = 0; b < ABLK; ++b) s += bh[b * NEXP + t];
        sc[t] = s;
    }
    __syncthreads();
    if (t == 0) {
        int s = 0;
        for (int e = 0; e < NEXP; ++e) { so_[e] = s; s += sc[e]; }
        so_[NEXP] = s;
        for (int e = 0; e <= NEXP; ++e) offsets[e] = so_[e];
        for (int e = 0; e < NEXP; ++e) counts[e] = sc[e];
    }
    __syncthreads();
    if (t < NEXP) {
        int run = so_[t];
        for (int b = 0; b < ABLK; ++b) {
            blockbase[b * NEXP + t] = run;
            run += bh[b * NEXP + t];
        }
    }
    __syncthreads();     // all reads of bh complete before chtab (alias) write
    if (t == 0) {
        int n = 0;
        for (int e = 0; e < NEXP; ++e) {
            int mch = (sc[e] + 255) >> 8;
            for (int m = 0; m < mch; ++m) chtab[n++] = (e << 16) | m;
        }
        nch[0] = n;
    }
}

// ---------------------------------------------------------------------------
// Stable slot assignment via wave ballots (deterministic, atomic-free).
// ---------------------------------------------------------------------------
__global__ __launch_bounds__(256) void k_assign(
    const int* __restrict__ topk, const int* __restrict__ blockbase,
    int* __restrict__ token_ids, int* __restrict__ slot_of)
{
    __shared__ int wcnt[4][NEXP];
    int tid = threadIdx.x, blk = blockIdx.x;
    int i = blk * 256 + tid;
    int e = topk[i];
    int lane = tid & 63, w = tid >> 6;
    unsigned long long ltmask = (1ull << lane) - 1ull;
    int rank_w = 0;
#pragma unroll
    for (int ee = 0; ee < NEXP; ++ee) {
        unsigned long long m = __ballot(e == ee);
        if (ee == e) rank_w = (int)__popcll(m & ltmask);
        if (lane == 0) wcnt[w][ee] = (int)__popcll(m);
    }
    __syncthreads();
    int pre = 0;
    for (int wv = 0; wv < w; ++wv) pre += wcnt[wv][e];
    int s = blockbase[blk * NEXP + e] + pre + rank_w;
    token_ids[s] = i >> 1;
    slot_of[i] = s;
}

// ===========================================================================
// 256x256 / BK=64 / 8-wave phase-split grouped GEMM (both layers).
//
// Wave w (0..7): wrM = (w>>2)*128, wcN = (w&3)*64; per-wave out = 128x64.
// acc[8][4] f32x4. LDS: As[2][256][64], Bs[2][256][64] bf16 = 128 KiB.
//
// T2 swizzle (derived for 128B rows, 16B units, both-sides):
//   LDS(row, unit j) holds global unit j ^ (row&7).
//   write side: global_load_lds dest linear; global src col unit
//               = (lane&7) ^ (lane>>3)   (per-thread constant)
//   read  side: frag(row, global unit u) at LDS unit u ^ (lane&7)
//               (row&7 == lane&7 for all frag rows)
// Staging per K-tile: 8 global_load_lds/thread (4 A + 4 B), issued at
// phase 0; boundary vmcnt(0) has ~4 phases of cover.
// ===========================================================================

#define GEMM_PHASES(NKV)                                                           \
    for (int kt = 0; kt < NKV; ++kt) {                                             \
        const short* Ac = &As[kt & 1][0][0];                                       \
        const short* Bc = &Bs[kt & 1][0][0];                                       \
        unsigned dstb = (unsigned)(((kt & 1) ^ 1) * 32768) + wb;                   \
        bf16x8 b_[4][2];                                                           \
        _Pragma("unroll")                                                          \
        for (int ph = 0; ph < 4; ++ph) {                                           \
            if (ph == 0) {                                                         \
                if (kt + 1 < NKV) {                                                \
                    int ko = (kt + 1) * 64;                                        \
                    __builtin_amdgcn_global_load_lds(AS1(aP0 + ko), AS3(AB + dstb),         16, 0, 0); \
                    __builtin_amdgcn_global_load_lds(AS1(aP1 + ko), AS3(AB + dstb + 8192),  16, 0, 0); \
                    __builtin_amdgcn_global_load_lds(AS1(aP2 + ko), AS3(AB + dstb + 16384), 16, 0, 0); \
                    __builtin_amdgcn_global_load_lds(AS1(aP3 + ko), AS3(AB + dstb + 24576), 16, 0, 0); \
                    __builtin_amdgcn_global_load_lds(AS1(bP0 + ko), AS3(BB + dstb),         16, 0, 0); \
                    __builtin_amdgcn_global_load_lds(AS1(bP1 + ko), AS3(BB + dstb + 8192),  16, 0, 0); \
                    __builtin_amdgcn_global_load_lds(AS1(bP2 + ko), AS3(BB + dstb + 16384), 16, 0, 0); \
                    __builtin_amdgcn_global_load_lds(AS1(bP3 + ko), AS3(BB + dstb + 24576), 16, 0, 0); \
                }                                                                  \
                _Pragma("unroll")                                                  \
                for (int nf = 0; nf < 4; ++nf) {                                   \
                    b_[nf][0] = *reinterpret_cast<const bf16x8*>(Bc + nf * 1024 + boff0);        \
                    b_[nf][1] = *reinterpret_cast<const bf16x8*>(Bc + nf * 1024 + (boff0 ^ 32)); \
                }                                                                  \
            }                                                                      \
            bf16x8 a_[2][2];                                                       \
            _Pragma("unroll")                                                      \
            for (int j = 0; j < 2; ++j) {                                          \
                const short* ar = Ac + (ph * 2 + j) * 1024;                        \
                a_[j][0] = *reinterpret_cast<const bf16x8*>(ar + aoff0);           \
                a_[j][1] = *reinterpret_cast<const bf16x8*>(ar + (aoff0 ^ 32));    \
            }                                                                      \
            __builtin_amdgcn_s_barrier();                                          \
            __builtin_amdgcn_s_setprio(1);                                         \
            _Pragma("unroll")                                                      \
            for (int j = 0; j < 2; ++j) {                                          \
                _Pragma("unroll")                                                  \
                for (int nf = 0; nf < 4; ++nf) {                                   \
                    acc[ph * 2 + j][nf] = __builtin_amdgcn_mfma_f32_16x16x32_bf16( \
                        a_[j][0], b_[nf][0], acc[ph * 2 + j][nf], 0, 0, 0);        \
                    acc[ph * 2 + j][nf] = __builtin_amdgcn_mfma_f32_16x16x32_bf16( \
                        a_[j][1], b_[nf][1], acc[ph * 2 + j][nf], 0, 0, 0);        \
                }                                                                  \
            }                                                                      \
            __builtin_amdgcn_s_setprio(0);                                         \
            if (ph == 3) asm volatile("s_waitcnt vmcnt(0)" ::: "memory");          \
            __builtin_amdgcn_s_barrier();                                          \
        }                                                                          \
    }

// ---------------------------------------------------------------------------
// Grouped GEMM1: h[slot][:] = relu( x[token(slot)][:] @ W1[e] + b1[e] )  (bf16)
// ---------------------------------------------------------------------------
__global__ __launch_bounds__(512) void k_gemm1(
    const bf16_t* __restrict__ xb, const bf16_t* __restrict__ w1t,
    const float* __restrict__ b1, bf16_t* __restrict__ hb,
    const int* __restrict__ token_ids, const int* __restrict__ counts,
    const int* __restrict__ offsets, const int* __restrict__ chtab,
    const int* __restrict__ nch)
{
    int bid   = xcd_swizzle();        // grid = MCHMAX*8 = 576
    int chunk = bid >> 3;
    int nc    = bid & 7;              // N chunk: 8 x 256 = 2048
    if (chunk >= nch[0]) return;
    int em = chtab[chunk];
    int e  = em >> 16;
    int mc = em & 0xffff;
    int count = counts[e];
    int base  = offsets[e];

    __shared__ short As[2][256][64];   // 64 KB
    __shared__ short Bs[2][256][64];   // 64 KB

    int t    = threadIdx.x;
    int w    = t >> 6;
    int lane = t & 63;
    int wrM  = (w >> 2) * 128;
    int wcN  = (w & 3) * 64;
    int lm   = lane & 15;
    int kq   = lane >> 4;
    int ru   = lane & 7;

    // read offsets (elements), swizzled
    int aoff0 = (wrM + lm) * 64 + ((kq ^ ru) * 8);
    int boff0 = (wcN + lm) * 64 + ((kq ^ ru) * 8);

    // staging: per-thread global source (pre-swizzled column unit)
    int rbase = t >> 3;                               // 0..63
    int c0s   = ((t & 7) ^ ((t >> 3) & 7)) * 8;       // elements
    unsigned wb = (unsigned)(w * 1024);               // LDS byte base per wave

    const bf16_t* wgt = w1t + (size_t)e * NHID * DIN;
    int r0 = imin_(mc * 256 +   0 + rbase, count - 1);
    int r1 = imin_(mc * 256 +  64 + rbase, count - 1);
    int r2 = imin_(mc * 256 + 128 + rbase, count - 1);
    int r3 = imin_(mc * 256 + 192 + rbase, count - 1);
    const bf16_t* aP0 = xb + (size_t)token_ids[base + r0] * DIN + c0s;
    const bf16_t* aP1 = xb + (size_t)token_ids[base + r1] * DIN + c0s;
    const bf16_t* aP2 = xb + (size_t)token_ids[base + r2] * DIN + c0s;
    const bf16_t* aP3 = xb + (size_t)token_ids[base + r3] * DIN + c0s;
    const bf16_t* bP0 = wgt + (size_t)(nc * 256 +   0 + rbase) * DIN + c0s;
    const bf16_t* bP1 = wgt + (size_t)(nc * 256 +  64 + rbase) * DIN + c0s;
    const bf16_t* bP2 = wgt + (size_t)(nc * 256 + 128 + rbase) * DIN + c0s;
    const bf16_t* bP3 = wgt + (size_t)(nc * 256 + 192 + rbase) * DIN + c0s;

    char* AB = (char*)&As[0][0][0];
    char* BB = (char*)&Bs[0][0][0];

    f32x4 acc[8][4];
#pragma unroll
    for (int m = 0; m < 8; ++m)
#pragma unroll
        for (int n = 0; n < 4; ++n) acc[m][n] = (f32x4){0.f, 0.f, 0.f, 0.f};

    // prologue: stage tile 0 into buf 0
    __builtin_amdgcn_global_load_lds(AS1(aP0), AS3(AB + wb),         16, 0, 0);
    __builtin_amdgcn_global_load_lds(AS1(aP1), AS3(AB + wb + 8192),  16, 0, 0);
    __builtin_amdgcn_global_load_lds(AS1(aP2), AS3(AB + wb + 16384), 16, 0, 0);
    __builtin_amdgcn_global_load_lds(AS1(aP3), AS3(AB + wb + 24576), 16, 0, 0);
    __builtin_amdgcn_global_load_lds(AS1(bP0), AS3(BB + wb),         16, 0, 0);
    __builtin_amdgcn_global_load_lds(AS1(bP1), AS3(BB + wb + 8192),  16, 0, 0);
    __builtin_amdgcn_global_load_lds(AS1(bP2), AS3(BB + wb + 16384), 16, 0, 0);
    __builtin_amdgcn_global_load_lds(AS1(bP3), AS3(BB + wb + 24576), 16, 0, 0);
    asm volatile("s_waitcnt vmcnt(0)" ::: "memory");
    __builtin_amdgcn_s_barrier();

    constexpr int NK = DIN / 64;    // 16 K-tiles
    GEMM_PHASES(NK)

    // epilogue: bias + relu -> bf16. D: col = lane&15, row = (lane>>4)*4 + q
    int rq = kq * 4;
#pragma unroll
    for (int nf = 0; nf < 4; ++nf) {
        int col  = nc * 256 + wcN + nf * 16 + lm;
        float bias = b1[e * NHID + col];
#pragma unroll
        for (int mf = 0; mf < 8; ++mf) {
            int gr0 = mc * 256 + wrM + mf * 16 + rq;
#pragma unroll
            for (int q = 0; q < 4; ++q) {
                int gr = gr0 + q;
                if (gr < count) {
                    float v = acc[mf][nf][q] + bias;
                    v = v > 0.f ? v : 0.f;
                    hb[(size_t)(base + gr) * NHID + col] = (bf16_t)v;
                }
            }
        }
    }
}

// ---------------------------------------------------------------------------
// Grouped GEMM2: so[slot][:] = h[slot][:] @ W2[e]   (bf16, no bias)
// ---------------------------------------------------------------------------
__global__ __launch_bounds__(512) void k_gemm2(
    const bf16_t* __restrict__ hb, const bf16_t* __restrict__ w2t,
    bf16_t* __restrict__ so,
    const int* __restrict__ counts, const int* __restrict__ offsets,
    const int* __restrict__ chtab, const int* __restrict__ nch)
{
    int bid   = xcd_swizzle();        // grid = MCHMAX*4 = 288
    int chunk = bid >> 2;
    int nc    = bid & 3;              // N chunk: 4 x 256 = 1024
    if (chunk >= nch[0]) return;
    int em = chtab[chunk];
    int e  = em >> 16;
    int mc = em & 0xffff;
    int count = counts[e];
    int base  = offsets[e];

    __shared__ short As[2][256][64];
    __shared__ short Bs[2][256][64];

    int t    = threadIdx.x;
    int w    = t >> 6;
    int lane = t & 63;
    int wrM  = (w >> 2) * 128;
    int wcN  = (w & 3) * 64;
    int lm   = lane & 15;
    int kq   = lane >> 4;
    int ru   = lane & 7;

    int aoff0 = (wrM + lm) * 64 + ((kq ^ ru) * 8);
    int boff0 = (wcN + lm) * 64 + ((kq ^ ru) * 8);

    int rbase = t >> 3;
    int c0s   = ((t & 7) ^ ((t >> 3) & 7)) * 8;
    unsigned wb = (unsigned)(w * 1024);

    const bf16_t* wgt = w2t + (size_t)e * DOUT * NHID;
    int r0 = imin_(mc * 256 +   0 + rbase, count - 1);
    int r1 = imin_(mc * 256 +  64 + rbase, count - 1);
    int r2 = imin_(mc * 256 + 128 + rbase, count - 1);
    int r3 = imin_(mc * 256 + 192 + rbase, count - 1);
    const bf16_t* aP0 = hb + (size_t)(base + r0) * NHID + c0s;
    const bf16_t* aP1 = hb + (size_t)(base + r1) * NHID + c0s;
    const bf16_t* aP2 = hb + (size_t)(base + r2) * NHID + c0s;
    const bf16_t* aP3 = hb + (size_t)(base + r3) * NHID + c0s;
    const bf16_t* bP0 = wgt + (size_t)(nc * 256 +   0 + rbase) * NHID + c0s;
    const bf16_t* bP1 = wgt + (size_t)(nc * 256 +  64 + rbase) * NHID + c0s;
    const bf16_t* bP2 = wgt + (size_t)(nc * 256 + 128 + rbase) * NHID + c0s;
    const bf16_t* bP3 = wgt + (size_t)(nc * 256 + 192 + rbase) * NHID + c0s;

    char* AB = (char*)&As[0][0][0];
    char* BB = (char*)&Bs[0][0][0];

    f32x4 acc[8][4];
#pragma unroll
    for (int m = 0; m < 8; ++m)
#pragma unroll
        for (int n = 0; n < 4; ++n) acc[m][n] = (f32x4){0.f, 0.f, 0.f, 0.f};

    __builtin_amdgcn_global_load_lds(AS1(aP0), AS3(AB + wb),         16, 0, 0);
    __builtin_amdgcn_global_load_lds(AS1(aP1), AS3(AB + wb + 8192),  16, 0, 0);
    __builtin_amdgcn_global_load_lds(AS1(aP2), AS3(AB + wb + 16384), 16, 0, 0);
    __builtin_amdgcn_global_load_lds(AS1(aP3), AS3(AB + wb + 24576), 16, 0, 0);
    __builtin_amdgcn_global_load_lds(AS1(bP0), AS3(BB + wb),         16, 0, 0);
    __builtin_amdgcn_global_load_lds(AS1(bP1), AS3(BB + wb + 8192),  16, 0, 0);
    __builtin_amdgcn_global_load_lds(AS1(bP2), AS3(BB + wb + 16384), 16, 0, 0);
    __builtin_amdgcn_global_load_lds(AS1(bP3), AS3(BB + wb + 24576), 16, 0, 0);
    asm volatile("s_waitcnt vmcnt(0)" ::: "memory");
    __builtin_amdgcn_s_barrier();

    constexpr int NK = NHID / 64;   // 32 K-tiles
    GEMM_PHASES(NK)

    int rq = kq * 4;
#pragma unroll
    for (int nf = 0; nf < 4; ++nf) {
        int col = nc * 256 + wcN + nf * 16 + lm;
#pragma unroll
        for (int mf = 0; mf < 8; ++mf) {
            int gr0 = mc * 256 + wrM + mf * 16 + rq;
#pragma unroll
            for (int q = 0; q < 4; ++q) {
                int gr = gr0 + q;
                if (gr < count)
                    so[(size_t)(base + gr) * DOUT + col] = (bf16_t)acc[mf][nf][q];
            }
        }
    }
}

// ---------------------------------------------------------------------------
// Combine: out[b][:] = so[s0][:] + so[s1][:] + b2[e0][:] + b2[e1][:]
// ---------------------------------------------------------------------------
__global__ __launch_bounds__(256) void k_combine(
    const bf16_t* __restrict__ so, const float* __restrict__ b2,
    const int* __restrict__ topk, const int* __restrict__ slot_of,
    float* __restrict__ out)
{
    int tid = threadIdx.x;
    int tok = blockIdx.x * 2 + (tid >> 7);
    int c0  = (tid & 127) * 8;
    int s0 = slot_of[2 * tok],  s1 = slot_of[2 * tok + 1];
    int e0 = topk[2 * tok],     e1 = topk[2 * tok + 1];
    bf16x8 a = *reinterpret_cast<const bf16x8*>(so + (size_t)s0 * DOUT + c0);
    bf16x8 b = *reinterpret_cast<const bf16x8*>(so + (size_t)s1 * DOUT + c0);
    const float* bb0 = b2 + (size_t)e0 * DOUT + c0;
    const float* bb1 = b2 + (size_t)e1 * DOUT + c0;
    float* op = out + (size_t)tok * DOUT + c0;
    float4 o0, o1;
    o0.x = (float)a[0] + (float)b[0] + bb0[0] + bb1[0];
    o0.y = (float)a[1] + (float)b[1] + bb0[1] + bb1[1];
    o0.z = (float)a[2] + (float)b[2] + bb0[2] + bb1[2];
    o0.w = (float)a[3] + (float)b[3] + bb0[3] + bb1[3];
    o1.x = (float)a[4] + (float)b[4] + bb0[4] + bb1[4];
    o1.y = (float)a[5] + (float)b[5] + bb0[5] + bb1[5];
    o1.z = (float)a[6] + (float)b[6] + bb0[6] + bb1[6];
    o1.w = (float)a[7] + (float)b[7] + bb0[7] + bb1[7];
    *reinterpret_cast<float4*>(op)     = o0;
    *reinterpret_cast<float4*>(op + 4) = o1;
}

// ---------------------------------------------------------------------------
extern "C" void kernel_launch(void* const* d_in, const int* in_sizes, int n_in,
                              void* d_out, int out_size, void* d_ws, size_t ws_size,
                              hipStream_t stream)
{
    const float* x  = (const float*)d_in[0];
    const float* Wg = (const float*)d_in[1];
    const float* bg = (const float*)d_in[2];
    const float* W1 = (const float*)d_in[3];
    const float* b1 = (const float*)d_in[4];
    const float* W2 = (const float*)d_in[5];
    const float* b2 = (const float*)d_in[6];
    float* out = (float*)d_out;

    // workspace layout (bytes)
    char* ws = (char*)d_ws;
    bf16_t* xb        = (bf16_t*)(ws);                 // 16,777,216
    bf16_t* w1t       = (bf16_t*)(ws + 16777216);      // 33,554,432  [e][h][din]
    bf16_t* w2t       = (bf16_t*)(ws + 50331648);      // 33,554,432  [e][dout][h]
    bf16_t* hb        = (bf16_t*)(ws + 83886080);      // 67,108,864
    int*    topk      = (int*)(ws + 150994944);        // 65,536
    int*    counts    = (int*)(ws + 151060480);        // 32
    int*    offsets   = (int*)(ws + 151060544);        // 64
    int*    token_ids = (int*)(ws + 151060608);        // 65,536
    int*    bh        = (int*)(ws + 151126144);        // 2,048
    int*    blockbase = (int*)(ws + 151128192);        // 2,048
    int*    slot_of   = (int*)(ws + 151130240);        // 65,536
    // total: 151,195,776 bytes (~144.2 MiB)

    // chunk table (<=72 ints) + count alias the bh region (bh consumed first).
    int* chtab = bh;            // 72 ints
    int* nch   = bh + MCHMAX;   // 1 int

    // so (bf16 slot outputs, 33.5 MB) reuses xb+w1t region (dead by gemm2).
    bf16_t* so = (bf16_t*)ws;
    // WgT (32 KB f32) lives in the hb region (hb first written by k_gemm1).
    float* wgT = (float*)hb;

    // Wg[din][e] -> wgT[e][din]
    k_wgT<<<(DIN * NEXP) / 256, 256, 0, stream>>>(Wg, wgT);

    // W1[e][din][h] -> w1t[e][h][din];  W2[e][h][dout] -> w2t[e][dout][h]
    k_transpose_cvt<<<NEXP * (DIN / 64) * (NHID / 64), 256, 0, stream>>>(W1, w1t, DIN, NHID);
    k_transpose_cvt<<<NEXP * (NHID / 64) * (DOUT / 64), 256, 0, stream>>>(W2, w2t, NHID, DOUT);

    k_gating<<<NTOK / 4, 256, 0, stream>>>(x, wgT, bg, xb, topk);
    k_hist<<<ABLK, 256, 0, stream>>>(topk, bh);
    k_scan2<<<1, 64, 0, stream>>>(bh, counts, offsets, blockbase, chtab, nch);
    k_assign<<<ABLK, 256, 0, stream>>>(topk, blockbase, token_ids, slot_of);

    k_gemm1<<<MCHMAX * 8, 512, 0, stream>>>(
        xb, w1t, b1, hb, token_ids, counts, offsets, chtab, nch);
    k_gemm2<<<MCHMAX * 4, 512, 0, stream>>>(
        hb, w2t, so, counts, offsets, chtab, nch);
    k_combine<<<NTOK / 2, 256, 0, stream>>>(so, b2, topk, slot_of, out);
}

// Round 5
// 313.343 us; speedup vs baseline: 1.0760x; 1.0760x over previous
//
#include <hip/hip_runtime.h>

// GranularMoELayer: B=8192, D_IN=1024, D_OUT=1024, E=8, K=2, H=2048
// Sparse top-2 routing (atomic-free, deterministic) + bf16 MFMA grouped GEMMs.
// R5 = R0 (best measured, 2-phase 128x128 loop) with BK 32->64:
//   - halves the number of per-K-step stage->drain->barrier serializations
//     (the measured dominant cost; m233-consistent), 2x MFMA per barrier.
//   - BK=64 rows are 128B -> would be a 16-way ds_read conflict; fixed with
//     the R4-VERIFIED both-sides XOR swizzle (pre-swizzled global source +
//     swizzled ds_read; measured SQ_LDS_BANK_CONFLICT == 0, refcheck passed).
//   - single-buffer 32KB LDS, full dead-block grid (R2 compact grid measured
//     slightly negative; reverted).

#define NTOK 8192
#define DIN  1024
#define DOUT 1024
#define NEXP 8
#define NHID 2048
#define NENT (NTOK * 2)          // 16384 routing entries
#define ABLK 64                  // assign/hist blocks (256 entries each)

typedef __bf16 bf16_t;
typedef __bf16 bf16x8 __attribute__((ext_vector_type(8)));
typedef __bf16 bf16x4 __attribute__((ext_vector_type(4)));
typedef float  f32x4  __attribute__((ext_vector_type(4)));

// CK-style address-space casts for global_load_lds
#define AS3(p) ((__attribute__((address_space(3))) void*)(unsigned)(unsigned long long)(p))
#define AS1(p) ((__attribute__((address_space(1))) void*)(unsigned long long)(p))

static __device__ __forceinline__ int imin_(int a, int b) { return a < b ? a : b; }

// XCD-aware bijective swizzle (gridDim.x % 8 == 0): each XCD gets a
// contiguous chunk of logical block ids -> per-expert weight panel L2-resident.
static __device__ __forceinline__ int xcd_swizzle() {
    int cpx = gridDim.x >> 3;
    return (blockIdx.x & 7) * cpx + (blockIdx.x >> 3);
}

// ---------------------------------------------------------------------------
// Transpose + f32->bf16 convert:  W[E][K_][N_] (f32) -> WT[E][N_][K_] (bf16)
// ---------------------------------------------------------------------------
__global__ __launch_bounds__(256) void k_transpose_cvt(
    const float* __restrict__ W, bf16_t* __restrict__ WT, int K_, int N_)
{
    __shared__ float tile[64][65];
    const int tilesK = K_ >> 6, tilesN = N_ >> 6;
    int bid = blockIdx.x;
    int e = bid / (tilesK * tilesN);
    int r = bid % (tilesK * tilesN);
    int tk = (r / tilesN) << 6;
    int tn = (r % tilesN) << 6;
    const float* Wb  = W  + (size_t)e * K_ * N_;
    bf16_t*      WTb = WT + (size_t)e * K_ * N_;
    int lr = threadIdx.x >> 6;   // 0..3
    int lc = threadIdx.x & 63;   // 0..63
#pragma unroll
    for (int i = 0; i < 16; ++i) {
        int row = i * 4 + lr;
        tile[row][lc] = Wb[(size_t)(tk + row) * N_ + tn + lc];
    }
    __syncthreads();
#pragma unroll
    for (int i = 0; i < 16; ++i) {
        int row = i * 4 + lr;
        WTb[(size_t)(tn + row) * K_ + tk + lc] = (bf16_t)tile[lc][row];
    }
}

// ---------------------------------------------------------------------------
// Tiny transpose: Wg[DIN][E] (f32) -> WgT[E][DIN] (f32)
// ---------------------------------------------------------------------------
__global__ __launch_bounds__(256) void k_wgT(
    const float* __restrict__ Wg, float* __restrict__ WgT)
{
    int i = blockIdx.x * 256 + threadIdx.x;
    int d = i >> 3, e = i & 7;
    WgT[e * DIN + d] = Wg[i];
}

// ---------------------------------------------------------------------------
// Gating: scores = x@Wg + bg (f32), top-2 -> topk. NO atomics.
// Fused: writes xb = bf16(x). One wave per token, all loads coalesced.
// ---------------------------------------------------------------------------
__global__ __launch_bounds__(256) void k_gating(
    const float* __restrict__ x, const float* __restrict__ WgT,
    const float* __restrict__ bg, bf16_t* __restrict__ xb,
    int* __restrict__ topk)
{
    int lane = threadIdx.x & 63;
    int tok  = blockIdx.x * 4 + (threadIdx.x >> 6);
    const float* xr  = x  + (size_t)tok * DIN;
    bf16_t*      xbr = xb + (size_t)tok * DIN;

    float4 xv[4];
#pragma unroll
    for (int i = 0; i < 4; ++i) {
        int idx = i * 256 + lane * 4;
        xv[i] = *reinterpret_cast<const float4*>(xr + idx);
        bf16x4 o;
        o[0] = (bf16_t)xv[i].x; o[1] = (bf16_t)xv[i].y;
        o[2] = (bf16_t)xv[i].z; o[3] = (bf16_t)xv[i].w;
        *reinterpret_cast<bf16x4*>(xbr + idx) = o;
    }

    float acc[NEXP];
#pragma unroll
    for (int e = 0; e < NEXP; ++e) {
        const float* we = WgT + (size_t)e * DIN;
        float a = 0.f;
#pragma unroll
        for (int i = 0; i < 4; ++i) {
            int idx = i * 256 + lane * 4;
            float4 w = *reinterpret_cast<const float4*>(we + idx);
            a += xv[i].x * w.x + xv[i].y * w.y + xv[i].z * w.z + xv[i].w * w.w;
        }
        acc[e] = a;
    }

#pragma unroll
    for (int e = 0; e < NEXP; ++e) {
#pragma unroll
        for (int off = 32; off >= 1; off >>= 1) acc[e] += __shfl_xor(acc[e], off);
    }
    if (lane == 0) {
        float s[NEXP];
#pragma unroll
        for (int e = 0; e < NEXP; ++e) s[e] = acc[e] + bg[e];
        int e0 = 0;
        for (int e = 1; e < NEXP; ++e) if (s[e] > s[e0]) e0 = e;   // ties -> lower idx
        int e1 = (e0 == 0) ? 1 : 0;
        for (int e = 0; e < NEXP; ++e) if (e != e0 && s[e] > s[e1]) e1 = e;
        topk[2 * tok]     = e0;
        topk[2 * tok + 1] = e1;
    }
}

// ---------------------------------------------------------------------------
// Per-block histogram of expert ids (LDS atomics only). ABLK blocks x 256.
// ---------------------------------------------------------------------------
__global__ __launch_bounds__(256) void k_hist(
    const int* __restrict__ topk, int* __restrict__ bh)
{
    __shared__ int h[NEXP];
    if (threadIdx.x < NEXP) h[threadIdx.x] = 0;
    __syncthreads();
    int i = blockIdx.x * 256 + threadIdx.x;
    atomicAdd(&h[topk[i]], 1);                 // LDS-scope, cheap
    __syncthreads();
    if (threadIdx.x < NEXP) bh[blockIdx.x * NEXP + threadIdx.x] = h[threadIdx.x];
}

// ---------------------------------------------------------------------------
// Scan: counts[e], offsets[9], per-block bases blockbase[ABLK][E]. 1 block.
// ---------------------------------------------------------------------------
__global__ void k_scan2(const int* __restrict__ bh, int* __restrict__ counts,
                        int* __restrict__ offsets, int* __restrict__ blockbase)
{
    __shared__ int sc[NEXP], so_[NEXP + 1];
    int t = threadIdx.x;
    if (t < NEXP) {
        int s = 0;
        for (int b = 0; b < ABLK; ++b) s += bh[b * NEXP + t];
        sc[t] = s;
    }
    __syncthreads();
    if (t == 0) {
        int s = 0;
        for (int e = 0; e < NEXP; ++e) { so_[e] = s; s += sc[e]; }
        so_[NEXP] = s;
        for (int e = 0; e <= NEXP; ++e) offsets[e] = so_[e];
        for (int e = 0; e < NEXP; ++e) counts[e] = sc[e];
    }
    __syncthreads();
    if (t < NEXP) {
        int run = so_[t];
        for (int b = 0; b < ABLK; ++b) {
            blockbase[b * NEXP + t] = run;
            run += bh[b * NEXP + t];
        }
    }
}

// ---------------------------------------------------------------------------
// Stable slot assignment via wave ballots (deterministic, atomic-free).
// entry i = (token i>>1, choice i&1). slot s -> token_ids[s]; slot_of[i] = s.
// ---------------------------------------------------------------------------
__global__ __launch_bounds__(256) void k_assign(
    const int* __restrict__ topk, const int* __restrict__ blockbase,
    int* __restrict__ token_ids, int* __restrict__ slot_of)
{
    __shared__ int wcnt[4][NEXP];
    int tid = threadIdx.x, blk = blockIdx.x;
    int i = blk * 256 + tid;
    int e = topk[i];
    int lane = tid & 63, w = tid >> 6;
    unsigned long long ltmask = (1ull << lane) - 1ull;
    int rank_w = 0;
#pragma unroll
    for (int ee = 0; ee < NEXP; ++ee) {
        unsigned long long m = __ballot(e == ee);
        if (ee == e) rank_w = (int)__popcll(m & ltmask);
        if (lane == 0) wcnt[w][ee] = (int)__popcll(m);
    }
    __syncthreads();
    int pre = 0;
    for (int wv = 0; wv < w; ++wv) pre += wcnt[wv][e];
    int s = blockbase[blk * NEXP + e] + pre + rank_w;
    token_ids[s] = i >> 1;
    slot_of[i] = s;
}

// ===========================================================================
// 128x128 / BK=64 / 4-wave grouped GEMM K-loop (both layers).
//
// LDS: As[128][64], Bs[128][64] bf16 (16 KB each, 32 KB total, single buffer).
// Staging (256 thr): wave w stages rows w*32..w*32+31 of A and of B;
//   instr j (0..3) -> LDS base w*4096 + j*1024 (linear dest, 8 rows/instr);
//   lane l writes row (l>>3), unit (l&7); global source col-unit is
//   pre-swizzled: unit_src = (l&7) ^ ((l>>3)&7)   [row base % 8 == 0].
// LDS content: LDS(row, unit u) = global(row, u ^ (row&7))  -> ds_read_b128
//   at unit (s*4+kq) ^ (row&7) is 2 lanes/bank = conflict-free (R4: 0 conflicts).
// K-step: stage 8 gload_lds -> __syncthreads (drain) -> 2 k-slices x 16 MFMA
//   -> __syncthreads.  Half the K-steps of BK=32 => half the drain count.
// ===========================================================================

// ---------------------------------------------------------------------------
// Grouped GEMM1: h[slot][:] = relu( x[token(slot)][:] @ W1[e] + b1[e] )  (bf16)
// ---------------------------------------------------------------------------
__global__ __launch_bounds__(256) void k_gemm1(
    const bf16_t* __restrict__ xb, const bf16_t* __restrict__ w1t,
    const float* __restrict__ b1, bf16_t* __restrict__ hb,
    const int* __restrict__ token_ids, const int* __restrict__ counts,
    const int* __restrict__ offsets)
{
    constexpr int MC = NTOK / 128;  // 64
    constexpr int NC = NHID / 128;  // 16
    int bid = xcd_swizzle();        // one expert per XCD (8192/8 = 1024 = MC*NC)
    int e  = bid / (MC * NC);
    int r  = bid % (MC * NC);
    int mc = r / NC;
    int nc = r % NC;
    int count = counts[e];
    if (mc * 128 >= count) return;
    int base = offsets[e];

    __shared__ short As[128][64];   // 16 KB
    __shared__ short Bs[128][64];   // 16 KB

    int t    = threadIdx.x;
    int lane = t & 63;
    int w    = t >> 6;
    int wr   = (w >> 1) * 64;
    int wc   = (w & 1) * 64;
    int lm   = lane & 15;
    int kq   = lane >> 4;           // 0..3
    int ru   = lane & 7;

    // staging source geometry (per-thread)
    int rl  = w * 32 + (lane >> 3);                 // row for instr j: rl + j*8
    int c0s = ((lane & 7) ^ ((lane >> 3) & 7)) * 8; // pre-swizzled col (elems)

    const bf16_t* aP0; const bf16_t* aP1; const bf16_t* aP2; const bf16_t* aP3;
    {
        int ra0 = imin_(mc * 128 + rl,      count - 1);
        int ra1 = imin_(mc * 128 + rl + 8,  count - 1);
        int ra2 = imin_(mc * 128 + rl + 16, count - 1);
        int ra3 = imin_(mc * 128 + rl + 24, count - 1);
        aP0 = xb + (size_t)token_ids[base + ra0] * DIN + c0s;
        aP1 = xb + (size_t)token_ids[base + ra1] * DIN + c0s;
        aP2 = xb + (size_t)token_ids[base + ra2] * DIN + c0s;
        aP3 = xb + (size_t)token_ids[base + ra3] * DIN + c0s;
    }
    const bf16_t* wbase = w1t + (size_t)e * NHID * DIN;
    const bf16_t* bP0 = wbase + (size_t)(nc * 128 + rl)      * DIN + c0s;
    const bf16_t* bP1 = wbase + (size_t)(nc * 128 + rl + 8)  * DIN + c0s;
    const bf16_t* bP2 = wbase + (size_t)(nc * 128 + rl + 16) * DIN + c0s;
    const bf16_t* bP3 = wbase + (size_t)(nc * 128 + rl + 24) * DIN + c0s;

    unsigned wlds = (unsigned)(w * 4096);   // wave-uniform LDS byte base

    f32x4 acc[4][4];
#pragma unroll
    for (int m = 0; m < 4; ++m)
#pragma unroll
        for (int n = 0; n < 4; ++n) acc[m][n] = (f32x4){0.f, 0.f, 0.f, 0.f};

    char* AtB = (char*)&As[0][0];
    char* BtB = (char*)&Bs[0][0];

    for (int k0 = 0; k0 < DIN; k0 += 64) {
        __builtin_amdgcn_global_load_lds(AS1(aP0 + k0), AS3(AtB + wlds),        16, 0, 0);
        __builtin_amdgcn_global_load_lds(AS1(aP1 + k0), AS3(AtB + wlds + 1024), 16, 0, 0);
        __builtin_amdgcn_global_load_lds(AS1(aP2 + k0), AS3(AtB + wlds + 2048), 16, 0, 0);
        __builtin_amdgcn_global_load_lds(AS1(aP3 + k0), AS3(AtB + wlds + 3072), 16, 0, 0);
        __builtin_amdgcn_global_load_lds(AS1(bP0 + k0), AS3(BtB + wlds),        16, 0, 0);
        __builtin_amdgcn_global_load_lds(AS1(bP1 + k0), AS3(BtB + wlds + 1024), 16, 0, 0);
        __builtin_amdgcn_global_load_lds(AS1(bP2 + k0), AS3(BtB + wlds + 2048), 16, 0, 0);
        __builtin_amdgcn_global_load_lds(AS1(bP3 + k0), AS3(BtB + wlds + 3072), 16, 0, 0);
        __syncthreads();

#pragma unroll
        for (int s = 0; s < 2; ++s) {
            int ko = ((kq ^ ru) * 8) ^ (s * 32);   // swizzled elem offset in row
            bf16x8 af[4], bfv[4];
#pragma unroll
            for (int m = 0; m < 4; ++m)
                af[m] = *reinterpret_cast<const bf16x8*>(&As[wr + m * 16 + lm][0] + ko);
#pragma unroll
            for (int n = 0; n < 4; ++n)
                bfv[n] = *reinterpret_cast<const bf16x8*>(&Bs[wc + n * 16 + lm][0] + ko);
#pragma unroll
            for (int m = 0; m < 4; ++m)
#pragma unroll
                for (int n = 0; n < 4; ++n)
                    acc[m][n] = __builtin_amdgcn_mfma_f32_16x16x32_bf16(af[m], bfv[n], acc[m][n], 0, 0, 0);
        }
        __syncthreads();
    }

    // epilogue: bias + relu -> bf16.  D layout: col = lane&15, row = (lane>>4)*4 + q
    int rq = kq * 4;
#pragma unroll
    for (int n = 0; n < 4; ++n) {
        int col  = nc * 128 + wc + n * 16 + lm;
        float bias = b1[e * NHID + col];
#pragma unroll
        for (int m = 0; m < 4; ++m) {
            int rbase = mc * 128 + wr + m * 16 + rq;
#pragma unroll
            for (int q = 0; q < 4; ++q) {
                int gr = rbase + q;
                if (gr < count) {
                    float v = acc[m][n][q] + bias;
                    v = v > 0.f ? v : 0.f;
                    hb[(size_t)(base + gr) * NHID + col] = (bf16_t)v;
                }
            }
        }
    }
}

// ---------------------------------------------------------------------------
// Grouped GEMM2: so[slot][:] = h[slot][:] @ W2[e]   (bf16, no bias, no atomics)
// ---------------------------------------------------------------------------
__global__ __launch_bounds__(256) void k_gemm2(
    const bf16_t* __restrict__ hb, const bf16_t* __restrict__ w2t,
    bf16_t* __restrict__ so,
    const int* __restrict__ counts, const int* __restrict__ offsets)
{
    constexpr int MC = NTOK / 128;  // 64
    constexpr int NC = DOUT / 128;  // 8
    int bid = xcd_swizzle();        // one expert per XCD (4096/8 = 512 = MC*NC)
    int e  = bid / (MC * NC);
    int r  = bid % (MC * NC);
    int mc = r / NC;
    int nc = r % NC;
    int count = counts[e];
    if (mc * 128 >= count) return;
    int base = offsets[e];

    __shared__ short As[128][64];
    __shared__ short Bs[128][64];

    int t    = threadIdx.x;
    int lane = t & 63;
    int w    = t >> 6;
    int wr   = (w >> 1) * 64;
    int wc   = (w & 1) * 64;
    int lm   = lane & 15;
    int kq   = lane >> 4;
    int ru   = lane & 7;

    int rl  = w * 32 + (lane >> 3);
    int c0s = ((lane & 7) ^ ((lane >> 3) & 7)) * 8;

    int ra0 = imin_(mc * 128 + rl,      count - 1);
    int ra1 = imin_(mc * 128 + rl + 8,  count - 1);
    int ra2 = imin_(mc * 128 + rl + 16, count - 1);
    int ra3 = imin_(mc * 128 + rl + 24, count - 1);
    const bf16_t* aP0 = hb + (size_t)(base + ra0) * NHID + c0s;
    const bf16_t* aP1 = hb + (size_t)(base + ra1) * NHID + c0s;
    const bf16_t* aP2 = hb + (size_t)(base + ra2) * NHID + c0s;
    const bf16_t* aP3 = hb + (size_t)(base + ra3) * NHID + c0s;
    const bf16_t* wbase = w2t + (size_t)e * DOUT * NHID;
    const bf16_t* bP0 = wbase + (size_t)(nc * 128 + rl)      * NHID + c0s;
    const bf16_t* bP1 = wbase + (size_t)(nc * 128 + rl + 8)  * NHID + c0s;
    const bf16_t* bP2 = wbase + (size_t)(nc * 128 + rl + 16) * NHID + c0s;
    const bf16_t* bP3 = wbase + (size_t)(nc * 128 + rl + 24) * NHID + c0s;

    unsigned wlds = (unsigned)(w * 4096);

    f32x4 acc[4][4];
#pragma unroll
    for (int m = 0; m < 4; ++m)
#pragma unroll
        for (int n = 0; n < 4; ++n) acc[m][n] = (f32x4){0.f, 0.f, 0.f, 0.f};

    char* AtB = (char*)&As[0][0];
    char* BtB = (char*)&Bs[0][0];

    for (int k0 = 0; k0 < NHID; k0 += 64) {
        __builtin_amdgcn_global_load_lds(AS1(aP0 + k0), AS3(AtB + wlds),        16, 0, 0);
        __builtin_amdgcn_global_load_lds(AS1(aP1 + k0), AS3(AtB + wlds + 1024), 16, 0, 0);
        __builtin_amdgcn_global_load_lds(AS1(aP2 + k0), AS3(AtB + wlds + 2048), 16, 0, 0);
        __builtin_amdgcn_global_load_lds(AS1(aP3 + k0), AS3(AtB + wlds + 3072), 16, 0, 0);
        __builtin_amdgcn_global_load_lds(AS1(bP0 + k0), AS3(BtB + wlds),        16, 0, 0);
        __builtin_amdgcn_global_load_lds(AS1(bP1 + k0), AS3(BtB + wlds + 1024), 16, 0, 0);
        __builtin_amdgcn_global_load_lds(AS1(bP2 + k0), AS3(BtB + wlds + 2048), 16, 0, 0);
        __builtin_amdgcn_global_load_lds(AS1(bP3 + k0), AS3(BtB + wlds + 3072), 16, 0, 0);
        __syncthreads();

#pragma unroll
        for (int s = 0; s < 2; ++s) {
            int ko = ((kq ^ ru) * 8) ^ (s * 32);
            bf16x8 af[4], bfv[4];
#pragma unroll
            for (int m = 0; m < 4; ++m)
                af[m] = *reinterpret_cast<const bf16x8*>(&As[wr + m * 16 + lm][0] + ko);
#pragma unroll
            for (int n = 0; n < 4; ++n)
                bfv[n] = *reinterpret_cast<const bf16x8*>(&Bs[wc + n * 16 + lm][0] + ko);
#pragma unroll
            for (int m = 0; m < 4; ++m)
#pragma unroll
                for (int n = 0; n < 4; ++n)
                    acc[m][n] = __builtin_amdgcn_mfma_f32_16x16x32_bf16(af[m], bfv[n], acc[m][n], 0, 0, 0);
        }
        __syncthreads();
    }

    int rq = kq * 4;
#pragma unroll
    for (int n = 0; n < 4; ++n) {
        int col = nc * 128 + wc + n * 16 + lm;
#pragma unroll
        for (int m = 0; m < 4; ++m) {
            int rbase = mc * 128 + wr + m * 16 + rq;
#pragma unroll
            for (int q = 0; q < 4; ++q) {
                int gr = rbase + q;
                if (gr < count)
                    so[(size_t)(base + gr) * DOUT + col] = (bf16_t)acc[m][n][q];
            }
        }
    }
}

// ---------------------------------------------------------------------------
// Combine: out[b][:] = so[s0][:] + so[s1][:] + b2[e0][:] + b2[e1][:]
// 2 tokens per block; fully coalesced; writes every output element.
// ---------------------------------------------------------------------------
__global__ __launch_bounds__(256) void k_combine(
    const bf16_t* __restrict__ so, const float* __restrict__ b2,
    const int* __restrict__ topk, const int* __restrict__ slot_of,
    float* __restrict__ out)
{
    int tid = threadIdx.x;
    int tok = blockIdx.x * 2 + (tid >> 7);
    int c0  = (tid & 127) * 8;
    int s0 = slot_of[2 * tok],  s1 = slot_of[2 * tok + 1];
    int e0 = topk[2 * tok],     e1 = topk[2 * tok + 1];
    bf16x8 a = *reinterpret_cast<const bf16x8*>(so + (size_t)s0 * DOUT + c0);
    bf16x8 b = *reinterpret_cast<const bf16x8*>(so + (size_t)s1 * DOUT + c0);
    const float* bb0 = b2 + (size_t)e0 * DOUT + c0;
    const float* bb1 = b2 + (size_t)e1 * DOUT + c0;
    float* op = out + (size_t)tok * DOUT + c0;
    float4 o0, o1;
    o0.x = (float)a[0] + (float)b[0] + bb0[0] + bb1[0];
    o0.y = (float)a[1] + (float)b[1] + bb0[1] + bb1[1];
    o0.z = (float)a[2] + (float)b[2] + bb0[2] + bb1[2];
    o0.w = (float)a[3] + (float)b[3] + bb0[3] + bb1[3];
    o1.x = (float)a[4] + (float)b[4] + bb0[4] + bb1[4];
    o1.y = (float)a[5] + (float)b[5] + bb0[5] + bb1[5];
    o1.z = (float)a[6] + (float)b[6] + bb0[6] + bb1[6];
    o1.w = (float)a[7] + (float)b[7] + bb0[7] + bb1[7];
    *reinterpret_cast<float4*>(op)     = o0;
    *reinterpret_cast<float4*>(op + 4) = o1;
}

// ---------------------------------------------------------------------------
extern "C" void kernel_launch(void* const* d_in, const int* in_sizes, int n_in,
                              void* d_out, int out_size, void* d_ws, size_t ws_size,
                              hipStream_t stream)
{
    const float* x  = (const float*)d_in[0];
    const float* Wg = (const float*)d_in[1];
    const float* bg = (const float*)d_in[2];
    const float* W1 = (const float*)d_in[3];
    const float* b1 = (const float*)d_in[4];
    const float* W2 = (const float*)d_in[5];
    const float* b2 = (const float*)d_in[6];
    float* out = (float*)d_out;

    // workspace layout (bytes)
    char* ws = (char*)d_ws;
    bf16_t* xb        = (bf16_t*)(ws);                 // 16,777,216
    bf16_t* w1t       = (bf16_t*)(ws + 16777216);      // 33,554,432  [e][h][din]
    bf16_t* w2t       = (bf16_t*)(ws + 50331648);      // 33,554,432  [e][dout][h]
    bf16_t* hb        = (bf16_t*)(ws + 83886080);      // 67,108,864
    int*    topk      = (int*)(ws + 150994944);        // 65,536
    int*    counts    = (int*)(ws + 151060480);        // 32
    int*    offsets   = (int*)(ws + 151060544);        // 64
    int*    token_ids = (int*)(ws + 151060608);        // 65,536
    int*    bh        = (int*)(ws + 151126144);        // 2,048
    int*    blockbase = (int*)(ws + 151128192);        // 2,048
    int*    slot_of   = (int*)(ws + 151130240);        // 65,536
    // total: 151,195,776 bytes (~144.2 MiB)

    // so (bf16 slot outputs, 33.5 MB) reuses xb+w1t region: both are dead
    // by the time k_gemm2 runs (stream-ordered).
    bf16_t* so = (bf16_t*)ws;
    // WgT (32 KB f32) lives in the hb region: hb first written by k_gemm1,
    // after gating finished reading WgT.
    float* wgT = (float*)hb;

    // Wg[din][e] -> wgT[e][din]
    k_wgT<<<(DIN * NEXP) / 256, 256, 0, stream>>>(Wg, wgT);

    // W1[e][din][h] -> w1t[e][h][din];  W2[e][h][dout] -> w2t[e][dout][h]
    k_transpose_cvt<<<NEXP * (DIN / 64) * (NHID / 64), 256, 0, stream>>>(W1, w1t, DIN, NHID);
    k_transpose_cvt<<<NEXP * (NHID / 64) * (DOUT / 64), 256, 0, stream>>>(W2, w2t, NHID, DOUT);

    k_gating<<<NTOK / 4, 256, 0, stream>>>(x, wgT, bg, xb, topk);
    k_hist<<<ABLK, 256, 0, stream>>>(topk, bh);
    k_scan2<<<1, 64, 0, stream>>>(bh, counts, offsets, blockbase);
    k_assign<<<ABLK, 256, 0, stream>>>(topk, blockbase, token_ids, slot_of);

    k_gemm1<<<NEXP * (NTOK / 128) * (NHID / 128), 256, 0, stream>>>(
        xb, w1t, b1, hb, token_ids, counts, offsets);
    k_gemm2<<<NEXP * (NTOK / 128) * (DOUT / 128), 256, 0, stream>>>(
        hb, w2t, so, counts, offsets);
    k_combine<<<NTOK / 2, 256, 0, stream>>>(so, b2, topk, slot_of, out);
}

// Round 6
// 297.010 us; speedup vs baseline: 1.1352x; 1.0550x over previous
//
#include <hip/hip_runtime.h>

// GranularMoELayer: B=8192, D_IN=1024, D_OUT=1024, E=8, K=2, H=2048
// Sparse top-2 routing (atomic-free, deterministic) + bf16 MFMA grouped GEMMs.
// R6 = R0 GEMM structure (best measured) + k_gather: tokens are physically
//     permuted into slot order ONCE (~50MB, ~9us) so gemm1's A-staging is
//     fully coalesced (contiguous rows), matching gemm2/m97. Theory: the
//     2-phase step time is CU vector-memory delivery-bound; gemm1's per-step
//     16-line A-gather (vs 4 contiguous lines) was the gemm1-vs-gemm2 rate
//     asymmetry (520 vs ~700 TF).
// Workspace re-planned so xs fits without growth; W2 transpose moved after
// gemm1 (w2t aliases dead xs).

#define NTOK 8192
#define DIN  1024
#define DOUT 1024
#define NEXP 8
#define NHID 2048
#define NENT (NTOK * 2)          // 16384 routing entries
#define ABLK 64                  // assign/hist blocks (256 entries each)

typedef __bf16 bf16_t;
typedef __bf16 bf16x8 __attribute__((ext_vector_type(8)));
typedef __bf16 bf16x4 __attribute__((ext_vector_type(4)));
typedef float  f32x4  __attribute__((ext_vector_type(4)));

// CK-style address-space casts for global_load_lds
#define AS3(p) ((__attribute__((address_space(3))) void*)(unsigned)(unsigned long long)(p))
#define AS1(p) ((__attribute__((address_space(1))) void*)(unsigned long long)(p))

static __device__ __forceinline__ int imin_(int a, int b) { return a < b ? a : b; }

// XCD-aware bijective swizzle (gridDim.x % 8 == 0): each XCD gets a
// contiguous chunk of logical block ids -> per-expert weight panel L2-resident.
static __device__ __forceinline__ int xcd_swizzle() {
    int cpx = gridDim.x >> 3;
    return (blockIdx.x & 7) * cpx + (blockIdx.x >> 3);
}

// ---------------------------------------------------------------------------
// Transpose + f32->bf16 convert:  W[E][K_][N_] (f32) -> WT[E][N_][K_] (bf16)
// ---------------------------------------------------------------------------
__global__ __launch_bounds__(256) void k_transpose_cvt(
    const float* __restrict__ W, bf16_t* __restrict__ WT, int K_, int N_)
{
    __shared__ float tile[64][65];
    const int tilesK = K_ >> 6, tilesN = N_ >> 6;
    int bid = blockIdx.x;
    int e = bid / (tilesK * tilesN);
    int r = bid % (tilesK * tilesN);
    int tk = (r / tilesN) << 6;
    int tn = (r % tilesN) << 6;
    const float* Wb  = W  + (size_t)e * K_ * N_;
    bf16_t*      WTb = WT + (size_t)e * K_ * N_;
    int lr = threadIdx.x >> 6;   // 0..3
    int lc = threadIdx.x & 63;   // 0..63
#pragma unroll
    for (int i = 0; i < 16; ++i) {
        int row = i * 4 + lr;
        tile[row][lc] = Wb[(size_t)(tk + row) * N_ + tn + lc];
    }
    __syncthreads();
#pragma unroll
    for (int i = 0; i < 16; ++i) {
        int row = i * 4 + lr;
        WTb[(size_t)(tn + row) * K_ + tk + lc] = (bf16_t)tile[lc][row];
    }
}

// ---------------------------------------------------------------------------
// Tiny transpose: Wg[DIN][E] (f32) -> WgT[E][DIN] (f32)
// ---------------------------------------------------------------------------
__global__ __launch_bounds__(256) void k_wgT(
    const float* __restrict__ Wg, float* __restrict__ WgT)
{
    int i = blockIdx.x * 256 + threadIdx.x;
    int d = i >> 3, e = i & 7;
    WgT[e * DIN + d] = Wg[i];
}

// ---------------------------------------------------------------------------
// Gating: scores = x@Wg + bg (f32), top-2 -> topk. NO atomics.
// Fused: writes xb = bf16(x). One wave per token, all loads coalesced.
// ---------------------------------------------------------------------------
__global__ __launch_bounds__(256) void k_gating(
    const float* __restrict__ x, const float* __restrict__ WgT,
    const float* __restrict__ bg, bf16_t* __restrict__ xb,
    int* __restrict__ topk)
{
    int lane = threadIdx.x & 63;
    int tok  = blockIdx.x * 4 + (threadIdx.x >> 6);
    const float* xr  = x  + (size_t)tok * DIN;
    bf16_t*      xbr = xb + (size_t)tok * DIN;

    float4 xv[4];
#pragma unroll
    for (int i = 0; i < 4; ++i) {
        int idx = i * 256 + lane * 4;
        xv[i] = *reinterpret_cast<const float4*>(xr + idx);
        bf16x4 o;
        o[0] = (bf16_t)xv[i].x; o[1] = (bf16_t)xv[i].y;
        o[2] = (bf16_t)xv[i].z; o[3] = (bf16_t)xv[i].w;
        *reinterpret_cast<bf16x4*>(xbr + idx) = o;
    }

    float acc[NEXP];
#pragma unroll
    for (int e = 0; e < NEXP; ++e) {
        const float* we = WgT + (size_t)e * DIN;
        float a = 0.f;
#pragma unroll
        for (int i = 0; i < 4; ++i) {
            int idx = i * 256 + lane * 4;
            float4 w = *reinterpret_cast<const float4*>(we + idx);
            a += xv[i].x * w.x + xv[i].y * w.y + xv[i].z * w.z + xv[i].w * w.w;
        }
        acc[e] = a;
    }

#pragma unroll
    for (int e = 0; e < NEXP; ++e) {
#pragma unroll
        for (int off = 32; off >= 1; off >>= 1) acc[e] += __shfl_xor(acc[e], off);
    }
    if (lane == 0) {
        float s[NEXP];
#pragma unroll
        for (int e = 0; e < NEXP; ++e) s[e] = acc[e] + bg[e];
        int e0 = 0;
        for (int e = 1; e < NEXP; ++e) if (s[e] > s[e0]) e0 = e;   // ties -> lower idx
        int e1 = (e0 == 0) ? 1 : 0;
        for (int e = 0; e < NEXP; ++e) if (e != e0 && s[e] > s[e1]) e1 = e;
        topk[2 * tok]     = e0;
        topk[2 * tok + 1] = e1;
    }
}

// ---------------------------------------------------------------------------
// Per-block histogram of expert ids (LDS atomics only). ABLK blocks x 256.
// ---------------------------------------------------------------------------
__global__ __launch_bounds__(256) void k_hist(
    const int* __restrict__ topk, int* __restrict__ bh)
{
    __shared__ int h[NEXP];
    if (threadIdx.x < NEXP) h[threadIdx.x] = 0;
    __syncthreads();
    int i = blockIdx.x * 256 + threadIdx.x;
    atomicAdd(&h[topk[i]], 1);                 // LDS-scope, cheap
    __syncthreads();
    if (threadIdx.x < NEXP) bh[blockIdx.x * NEXP + threadIdx.x] = h[threadIdx.x];
}

// ---------------------------------------------------------------------------
// Scan: counts[e], offsets[9], per-block bases blockbase[ABLK][E]. 1 block.
// ---------------------------------------------------------------------------
__global__ void k_scan2(const int* __restrict__ bh, int* __restrict__ counts,
                        int* __restrict__ offsets, int* __restrict__ blockbase)
{
    __shared__ int sc[NEXP], so_[NEXP + 1];
    int t = threadIdx.x;
    if (t < NEXP) {
        int s = 0;
        for (int b = 0; b < ABLK; ++b) s += bh[b * NEXP + t];
        sc[t] = s;
    }
    __syncthreads();
    if (t == 0) {
        int s = 0;
        for (int e = 0; e < NEXP; ++e) { so_[e] = s; s += sc[e]; }
        so_[NEXP] = s;
        for (int e = 0; e <= NEXP; ++e) offsets[e] = so_[e];
        for (int e = 0; e < NEXP; ++e) counts[e] = sc[e];
    }
    __syncthreads();
    if (t < NEXP) {
        int run = so_[t];
        for (int b = 0; b < ABLK; ++b) {
            blockbase[b * NEXP + t] = run;
            run += bh[b * NEXP + t];
        }
    }
}

// ---------------------------------------------------------------------------
// Stable slot assignment via wave ballots (deterministic, atomic-free).
// entry i = (token i>>1, choice i&1). slot s -> token_ids[s]; slot_of[i] = s.
// ---------------------------------------------------------------------------
__global__ __launch_bounds__(256) void k_assign(
    const int* __restrict__ topk, const int* __restrict__ blockbase,
    int* __restrict__ token_ids, int* __restrict__ slot_of)
{
    __shared__ int wcnt[4][NEXP];
    int tid = threadIdx.x, blk = blockIdx.x;
    int i = blk * 256 + tid;
    int e = topk[i];
    int lane = tid & 63, w = tid >> 6;
    unsigned long long ltmask = (1ull << lane) - 1ull;
    int rank_w = 0;
#pragma unroll
    for (int ee = 0; ee < NEXP; ++ee) {
        unsigned long long m = __ballot(e == ee);
        if (ee == e) rank_w = (int)__popcll(m & ltmask);
        if (lane == 0) wcnt[w][ee] = (int)__popcll(m);
    }
    __syncthreads();
    int pre = 0;
    for (int wv = 0; wv < w; ++wv) pre += wcnt[wv][e];
    int s = blockbase[blk * NEXP + e] + pre + rank_w;
    token_ids[s] = i >> 1;
    slot_of[i] = s;
}

// ---------------------------------------------------------------------------
// Gather: xs[slot][:] = xb[token_ids[slot]][:]   (bf16, fully coalesced)
// 2 slots per 256-thread block; 128 threads x 16B per slot row (2 KB).
// Pays the token permutation ONCE so gemm1's A-staging is contiguous.
// ---------------------------------------------------------------------------
__global__ __launch_bounds__(256) void k_gather(
    const bf16_t* __restrict__ xb, const int* __restrict__ token_ids,
    bf16_t* __restrict__ xs)
{
    int tid  = threadIdx.x;
    int slot = blockIdx.x * 2 + (tid >> 7);
    int c0   = (tid & 127) * 8;
    int tok  = token_ids[slot];
    bf16x8 v = *reinterpret_cast<const bf16x8*>(xb + (size_t)tok * DIN + c0);
    *reinterpret_cast<bf16x8*>(xs + (size_t)slot * DIN + c0) = v;
}

// ---------------------------------------------------------------------------
// Grouped GEMM1: h[slot][:] = relu( xs[slot][:] @ W1[e] + b1[e] )  (bf16)
// 128x128 tile, BK=32, 4 waves, mfma_f32_16x16x32_bf16, global_load_lds w=16.
// A rows contiguous (slot-ordered xs) -> staging fully coalesced.
// ---------------------------------------------------------------------------
__global__ __launch_bounds__(256) void k_gemm1(
    const bf16_t* __restrict__ xs, const bf16_t* __restrict__ w1t,
    const float* __restrict__ b1, bf16_t* __restrict__ hb,
    const int* __restrict__ counts, const int* __restrict__ offsets)
{
    constexpr int MC = NTOK / 128;  // 64
    constexpr int NC = NHID / 128;  // 16
    int bid = xcd_swizzle();        // one expert per XCD (8192/8 = 1024 = MC*NC)
    int e  = bid / (MC * NC);
    int r  = bid % (MC * NC);
    int mc = r / NC;
    int nc = r % NC;
    int count = counts[e];
    if (mc * 128 >= count) return;
    int base = offsets[e];

    __shared__ short At[128][32];
    __shared__ short Bt[128][32];

    int t    = threadIdx.x;
    int lane = t & 63;
    int w    = t >> 6;
    int wr   = (w >> 1) * 64;
    int wc   = (w & 1) * 64;

    int r0 = t >> 2;            // 0..63
    int r1 = 64 + r0;           // 64..127
    int c0 = (t & 3) * 8;       // k-offset (elements)

    int row0 = imin_(mc * 128 + r0, count - 1);
    int row1 = imin_(mc * 128 + r1, count - 1);
    const bf16_t* a0 = xs + (size_t)(base + row0) * DIN + c0;
    const bf16_t* a1 = xs + (size_t)(base + row1) * DIN + c0;
    const bf16_t* wbase = w1t + (size_t)e * NHID * DIN;
    const bf16_t* bp0 = wbase + (size_t)(nc * 128 + r0) * DIN + c0;
    const bf16_t* bp1 = wbase + (size_t)(nc * 128 + r1) * DIN + c0;

    unsigned lds0 = (unsigned)(t & 192) * 16;     // wave-uniform base, bytes
    unsigned lds1 = 4096u + lds0;

    f32x4 acc[4][4];
#pragma unroll
    for (int m = 0; m < 4; ++m)
#pragma unroll
        for (int n = 0; n < 4; ++n) acc[m][n] = (f32x4){0.f, 0.f, 0.f, 0.f};

    char* AtB = (char*)&At[0][0];
    char* BtB = (char*)&Bt[0][0];

    for (int k0 = 0; k0 < DIN; k0 += 32) {
        __builtin_amdgcn_global_load_lds(AS1(a0 + k0),  AS3(AtB + lds0), 16, 0, 0);
        __builtin_amdgcn_global_load_lds(AS1(a1 + k0),  AS3(AtB + lds1), 16, 0, 0);
        __builtin_amdgcn_global_load_lds(AS1(bp0 + k0), AS3(BtB + lds0), 16, 0, 0);
        __builtin_amdgcn_global_load_lds(AS1(bp1 + k0), AS3(BtB + lds1), 16, 0, 0);
        __syncthreads();

        bf16x8 af[4], bfv[4];
        int kr = (lane >> 4) * 8;
#pragma unroll
        for (int m = 0; m < 4; ++m)
            af[m] = *reinterpret_cast<const bf16x8*>(&At[wr + m * 16 + (lane & 15)][kr]);
#pragma unroll
        for (int n = 0; n < 4; ++n)
            bfv[n] = *reinterpret_cast<const bf16x8*>(&Bt[wc + n * 16 + (lane & 15)][kr]);
#pragma unroll
        for (int m = 0; m < 4; ++m)
#pragma unroll
            for (int n = 0; n < 4; ++n)
                acc[m][n] = __builtin_amdgcn_mfma_f32_16x16x32_bf16(af[m], bfv[n], acc[m][n], 0, 0, 0);
        __syncthreads();
    }

    // epilogue: bias + relu -> bf16.  D layout: col = lane&15, row = (lane>>4)*4 + q
    int cl = lane & 15;
    int rq = (lane >> 4) * 4;
#pragma unroll
    for (int n = 0; n < 4; ++n) {
        int col  = nc * 128 + wc + n * 16 + cl;
        float bias = b1[e * NHID + col];
#pragma unroll
        for (int m = 0; m < 4; ++m) {
            int rbase = mc * 128 + wr + m * 16 + rq;
#pragma unroll
            for (int q = 0; q < 4; ++q) {
                int gr = rbase + q;
                if (gr < count) {
                    float v = acc[m][n][q] + bias;
                    v = v > 0.f ? v : 0.f;
                    hb[(size_t)(base + gr) * NHID + col] = (bf16_t)v;
                }
            }
        }
    }
}

// ---------------------------------------------------------------------------
// Grouped GEMM2: so[slot][:] = h[slot][:] @ W2[e]   (bf16, no bias, no atomics)
// ---------------------------------------------------------------------------
__global__ __launch_bounds__(256) void k_gemm2(
    const bf16_t* __restrict__ hb, const bf16_t* __restrict__ w2t,
    bf16_t* __restrict__ so,
    const int* __restrict__ counts, const int* __restrict__ offsets)
{
    constexpr int MC = NTOK / 128;  // 64
    constexpr int NC = DOUT / 128;  // 8
    int bid = xcd_swizzle();        // one expert per XCD (4096/8 = 512 = MC*NC)
    int e  = bid / (MC * NC);
    int r  = bid % (MC * NC);
    int mc = r / NC;
    int nc = r % NC;
    int count = counts[e];
    if (mc * 128 >= count) return;
    int base = offsets[e];

    __shared__ short At[128][32];
    __shared__ short Bt[128][32];

    int t    = threadIdx.x;
    int lane = t & 63;
    int w    = t >> 6;
    int wr   = (w >> 1) * 64;
    int wc   = (w & 1) * 64;

    int r0 = t >> 2;
    int r1 = 64 + r0;
    int c0 = (t & 3) * 8;

    int row0 = imin_(mc * 128 + r0, count - 1);
    int row1 = imin_(mc * 128 + r1, count - 1);
    const bf16_t* a0 = hb + (size_t)(base + row0) * NHID + c0;
    const bf16_t* a1 = hb + (size_t)(base + row1) * NHID + c0;
    const bf16_t* wbase = w2t + (size_t)e * DOUT * NHID;
    const bf16_t* bp0 = wbase + (size_t)(nc * 128 + r0) * NHID + c0;
    const bf16_t* bp1 = wbase + (size_t)(nc * 128 + r1) * NHID + c0;

    unsigned lds0 = (unsigned)(t & 192) * 16;
    unsigned lds1 = 4096u + lds0;

    f32x4 acc[4][4];
#pragma unroll
    for (int m = 0; m < 4; ++m)
#pragma unroll
        for (int n = 0; n < 4; ++n) acc[m][n] = (f32x4){0.f, 0.f, 0.f, 0.f};

    char* AtB = (char*)&At[0][0];
    char* BtB = (char*)&Bt[0][0];

    for (int k0 = 0; k0 < NHID; k0 += 32) {
        __builtin_amdgcn_global_load_lds(AS1(a0 + k0),  AS3(AtB + lds0), 16, 0, 0);
        __builtin_amdgcn_global_load_lds(AS1(a1 + k0),  AS3(AtB + lds1), 16, 0, 0);
        __builtin_amdgcn_global_load_lds(AS1(bp0 + k0), AS3(BtB + lds0), 16, 0, 0);
        __builtin_amdgcn_global_load_lds(AS1(bp1 + k0), AS3(BtB + lds1), 16, 0, 0);
        __syncthreads();

        bf16x8 af[4], bfv[4];
        int kr = (lane >> 4) * 8;
#pragma unroll
        for (int m = 0; m < 4; ++m)
            af[m] = *reinterpret_cast<const bf16x8*>(&At[wr + m * 16 + (lane & 15)][kr]);
#pragma unroll
        for (int n = 0; n < 4; ++n)
            bfv[n] = *reinterpret_cast<const bf16x8*>(&Bt[wc + n * 16 + (lane & 15)][kr]);
#pragma unroll
        for (int m = 0; m < 4; ++m)
#pragma unroll
            for (int n = 0; n < 4; ++n)
                acc[m][n] = __builtin_amdgcn_mfma_f32_16x16x32_bf16(af[m], bfv[n], acc[m][n], 0, 0, 0);
        __syncthreads();
    }

    int cl = lane & 15;
    int rq = (lane >> 4) * 4;
#pragma unroll
    for (int n = 0; n < 4; ++n) {
        int col = nc * 128 + wc + n * 16 + cl;
#pragma unroll
        for (int m = 0; m < 4; ++m) {
            int rbase = mc * 128 + wr + m * 16 + rq;
#pragma unroll
            for (int q = 0; q < 4; ++q) {
                int gr = rbase + q;
                if (gr < count)
                    so[(size_t)(base + gr) * DOUT + col] = (bf16_t)acc[m][n][q];
            }
        }
    }
}

// ---------------------------------------------------------------------------
// Combine: out[b][:] = so[s0][:] + so[s1][:] + b2[e0][:] + b2[e1][:]
// 2 tokens per block; fully coalesced; writes every output element.
// ---------------------------------------------------------------------------
__global__ __launch_bounds__(256) void k_combine(
    const bf16_t* __restrict__ so, const float* __restrict__ b2,
    const int* __restrict__ topk, const int* __restrict__ slot_of,
    float* __restrict__ out)
{
    int tid = threadIdx.x;
    int tok = blockIdx.x * 2 + (tid >> 7);
    int c0  = (tid & 127) * 8;
    int s0 = slot_of[2 * tok],  s1 = slot_of[2 * tok + 1];
    int e0 = topk[2 * tok],     e1 = topk[2 * tok + 1];
    bf16x8 a = *reinterpret_cast<const bf16x8*>(so + (size_t)s0 * DOUT + c0);
    bf16x8 b = *reinterpret_cast<const bf16x8*>(so + (size_t)s1 * DOUT + c0);
    const float* bb0 = b2 + (size_t)e0 * DOUT + c0;
    const float* bb1 = b2 + (size_t)e1 * DOUT + c0;
    float* op = out + (size_t)tok * DOUT + c0;
    float4 o0, o1;
    o0.x = (float)a[0] + (float)b[0] + bb0[0] + bb1[0];
    o0.y = (float)a[1] + (float)b[1] + bb0[1] + bb1[1];
    o0.z = (float)a[2] + (float)b[2] + bb0[2] + bb1[2];
    o0.w = (float)a[3] + (float)b[3] + bb0[3] + bb1[3];
    o1.x = (float)a[4] + (float)b[4] + bb0[4] + bb1[4];
    o1.y = (float)a[5] + (float)b[5] + bb0[5] + bb1[5];
    o1.z = (float)a[6] + (float)b[6] + bb0[6] + bb1[6];
    o1.w = (float)a[7] + (float)b[7] + bb0[7] + bb1[7];
    *reinterpret_cast<float4*>(op)     = o0;
    *reinterpret_cast<float4*>(op + 4) = o1;
}

// ---------------------------------------------------------------------------
extern "C" void kernel_launch(void* const* d_in, const int* in_sizes, int n_in,
                              void* d_out, int out_size, void* d_ws, size_t ws_size,
                              hipStream_t stream)
{
    const float* x  = (const float*)d_in[0];
    const float* Wg = (const float*)d_in[1];
    const float* bg = (const float*)d_in[2];
    const float* W1 = (const float*)d_in[3];
    const float* b1 = (const float*)d_in[4];
    const float* W2 = (const float*)d_in[5];
    const float* b2 = (const float*)d_in[6];
    float* out = (float*)d_out;

    // workspace layout (bytes), liveness-packed (peak ~134.4 MiB < 151 MiB):
    //   [0,        33.5M)  xs   (slot-ordered A for gemm1)   | later: w2t
    //   [33.5M,    67M)    xb   (bf16 tokens, dead after gather)
    //                      then w1t (W1^T, written after gather) | later: so
    //   [67M,      134M)   hb   (gemm1 out)  | wgT (32KB) lives here pre-gemm1
    //   [134M,     ...)    int buffers
    char* ws = (char*)d_ws;
    bf16_t* xs        = (bf16_t*)(ws);                 // 33,554,432
    bf16_t* xb        = (bf16_t*)(ws + 33554432);      // 16,777,216 (dead after gather)
    bf16_t* w1t       = (bf16_t*)(ws + 33554432);      // 33,554,432 (overwrites xb)
    bf16_t* hb        = (bf16_t*)(ws + 67108864);      // 67,108,864
    int*    topk      = (int*)(ws + 134217728);        // 65,536
    int*    counts    = (int*)(ws + 134283264);        // 64
    int*    offsets   = (int*)(ws + 134283328);        // 64
    int*    token_ids = (int*)(ws + 134283392);        // 65,536
    int*    bh        = (int*)(ws + 134348928);        // 2,048
    int*    blockbase = (int*)(ws + 134350976);        // 2,048
    int*    slot_of   = (int*)(ws + 134353024);        // 65,536
    // w2t overwrites xs after gemm1; so overwrites w1t after gemm1.
    bf16_t* w2t = (bf16_t*)(ws);                       // 33,554,432
    bf16_t* so  = (bf16_t*)(ws + 33554432);            // 33,554,432
    // WgT (32 KB f32) lives in the hb region (hb first written by k_gemm1,
    // after gating finished reading WgT).
    float* wgT = (float*)hb;

    // Wg[din][e] -> wgT[e][din]
    k_wgT<<<(DIN * NEXP) / 256, 256, 0, stream>>>(Wg, wgT);

    // gating + routing
    k_gating<<<NTOK / 4, 256, 0, stream>>>(x, wgT, bg, xb, topk);
    k_hist<<<ABLK, 256, 0, stream>>>(topk, bh);
    k_scan2<<<1, 64, 0, stream>>>(bh, counts, offsets, blockbase);
    k_assign<<<ABLK, 256, 0, stream>>>(topk, blockbase, token_ids, slot_of);

    // permute tokens into slot order (xb dead afterwards)
    k_gather<<<NENT / 2, 256, 0, stream>>>(xb, token_ids, xs);

    // W1[e][din][h] -> w1t[e][h][din]  (overwrites dead xb region)
    k_transpose_cvt<<<NEXP * (DIN / 64) * (NHID / 64), 256, 0, stream>>>(W1, w1t, DIN, NHID);

    k_gemm1<<<NEXP * (NTOK / 128) * (NHID / 128), 256, 0, stream>>>(
        xs, w1t, b1, hb, counts, offsets);

    // W2[e][h][dout] -> w2t[e][dout][h]  (overwrites dead xs region)
    k_transpose_cvt<<<NEXP * (NHID / 64) * (DOUT / 64), 256, 0, stream>>>(W2, w2t, NHID, DOUT);

    k_gemm2<<<NEXP * (NTOK / 128) * (DOUT / 128), 256, 0, stream>>>(
        hb, w2t, so, counts, offsets);
    k_combine<<<NTOK / 2, 256, 0, stream>>>(so, b2, topk, slot_of, out);
}